// Round 4
// baseline (138.831 us; speedup 1.0000x reference)
//
#include <hip/hip_runtime.h>
#include <hip/hip_bf16.h>

#define N_NODES 100000
#define DEGREE 32
#define N_PAIRS 8192
#define FEAT 9
#define HID 20
#define NOUT 15
#define FPAD 16   // padded row stride (elements) for the bf16 t table (32B rows)

#define NPB 28    // nodes per chunk in K1 (28*9 = 252 active lanes of 256)
#define NCH1 4    // chunks per block in K1 -> 112 nodes/block, grid 893
#define PPB 8     // pairs per chunk in K2 (8*30 = 240 active lanes of 256)
#define NCH2 4    // chunks per block in K2 -> 32 pairs/block, grid 256 (1 round)

// ---------------------------------------------------------------------------
// K1: fused enc1-mean + node MLP. Direct fp32 feat gather (grouped lanes: the
//   9 lanes of a node share each 36B row -> ~1.5 line-transactions/row, and a
//   wave's gather instruction touches only ~7 distinct lines). t stored bf16
//   at stride 16 so K2's row gathers are one aligned 32B segment.
//   Chunk-loop x4 amortizes the 660-float weight staging and cuts the grid
//   3572 -> 893 blocks.
// ---------------------------------------------------------------------------
__global__ __launch_bounds__(256) void k_node_all(
    const int* __restrict__ adj,
    const float* __restrict__ feat,
    const float* __restrict__ W1,   // [HID][2*FEAT]
    const float* __restrict__ W2,   // [NOUT][HID]
    __hip_bfloat16* __restrict__ t_ws) {
  __shared__ float sW1[HID * 2 * FEAT];   // 360
  __shared__ float sW2[NOUT * HID];       // 300
  __shared__ float sComb[NPB][2 * FEAT];  // 28 x 18
  __shared__ float sH[NPB][HID];          // 28 x 20

  int tid = threadIdx.x;
  for (int i = tid; i < HID * 2 * FEAT; i += 256) sW1[i] = W1[i];
  for (int i = tid; i < NOUT * HID; i += 256) sW2[i] = W2[i];
  // first chunk's phase-1 barrier also covers the weight staging

  int bbase = blockIdx.x * (NPB * NCH1);

  for (int ch = 0; ch < NCH1; ++ch) {
    int base = bbase + ch * NPB;

    // phase 1: [self feat | neighbor mean] -> sComb (fp32 gathers)
    if (tid < NPB * FEAT) {
      int nl = tid / FEAT;
      int j = tid - nl * FEAT;
      int n = base + nl;
      if (n < N_NODES) {
        const int4* arow4 = (const int4*)(adj + (size_t)n * DEGREE);
        float s = 0.f;
#pragma unroll
        for (int c = 0; c < DEGREE / 4; ++c) {
          int4 a4 = arow4[c];
          s += feat[(size_t)a4.x * FEAT + j];
          s += feat[(size_t)a4.y * FEAT + j];
          s += feat[(size_t)a4.z * FEAT + j];
          s += feat[(size_t)a4.w * FEAT + j];
        }
        sComb[nl][j] = feat[(size_t)n * FEAT + j];
        sComb[nl][FEAT + j] = s * (1.0f / DEGREE);
      }
    }
    __syncthreads();

    // phase 2: h1 = relu(W1 @ comb), one thread per (node, hid)
    for (int idx = tid; idx < NPB * HID; idx += 256) {
      int nl = idx / HID;
      int i = idx - nl * HID;
      if (base + nl < N_NODES) {
        float acc = 0.f;
#pragma unroll
        for (int j = 0; j < 2 * FEAT; ++j)
          acc += sW1[i * 2 * FEAT + j] * sComb[nl][j];
        sH[nl][i] = fmaxf(acc, 0.f);
      }
    }
    __syncthreads();

    // phase 3: t = W2 @ h1 (linear; relu comes after the enc2 mean).
    // Safe without a trailing barrier: next chunk's phase-2 writes to sH sit
    // behind the next chunk's first barrier; phase-1 only touches sComb.
    for (int idx = tid; idx < NPB * NOUT; idx += 256) {
      int nl = idx / NOUT;
      int d = idx - nl * NOUT;
      int n = base + nl;
      if (n < N_NODES) {
        float acc = 0.f;
#pragma unroll
        for (int i = 0; i < HID; ++i) acc += sW2[d * HID + i] * sH[nl][i];
        t_ws[(size_t)n * FPAD + d] = __float2bfloat16(acc);
      }
    }
    __syncthreads();
  }
}

// ---------------------------------------------------------------------------
// K2: fused enc2 endpoint aggregation + pair MLP. t rows are bf16 stride-16:
//   the 15-lane group's 30B gather is exactly one aligned 32B segment.
//   Chunk-loop x4 -> 32 pairs/block, grid 256 = one block-round on 256 CUs.
// ---------------------------------------------------------------------------
__global__ __launch_bounds__(256) void k_pair_all(
    const int* __restrict__ to_pred,
    const int* __restrict__ adj,
    const __hip_bfloat16* __restrict__ t_ws,
    const float* __restrict__ fc1_w,  // [15][30]
    const float* __restrict__ fc1_b,  // [15]
    const float* __restrict__ fc2_w,  // [1][15]
    const float* __restrict__ fc2_b,  // [1]
    float* __restrict__ out) {
  __shared__ float s1[15 * 30];
  __shared__ float b1v[15];
  __shared__ float s2v[15];
  __shared__ float b2v;
  __shared__ float sE[PPB][30];
  __shared__ float sHh[PPB][15];

  int tid = threadIdx.x;
  for (int i = tid; i < 15 * 30; i += 256) s1[i] = fc1_w[i];
  if (tid < 15) {
    b1v[tid] = fc1_b[tid];
    s2v[tid] = fc2_w[tid];
  }
  if (tid == 0) b2v = fc2_b[0];

  int bbase = blockIdx.x * (PPB * NCH2);

  for (int ch = 0; ch < NCH2; ++ch) {
    int pbase = bbase + ch * PPB;

    // phase 1: endpoint aggregate (self + 32 neighbors of t, relu(mean))
    if (tid < PPB * 30) {
      int pl = tid / 30;
      int slot = tid - pl * 30;
      int side = slot / 15;
      int d = slot - side * 15;
      int p = pbase + pl;               // 8192 % 32 == 0: always in range
      int node = to_pred[2 * p + side];
      const int4* arow4 = (const int4*)(adj + (size_t)node * DEGREE);
      float s = __bfloat162float(t_ws[(size_t)node * FPAD + d]);  // self term
#pragma unroll
      for (int c = 0; c < DEGREE / 4; ++c) {
        int4 a4 = arow4[c];
        s += __bfloat162float(t_ws[(size_t)a4.x * FPAD + d]);
        s += __bfloat162float(t_ws[(size_t)a4.y * FPAD + d]);
        s += __bfloat162float(t_ws[(size_t)a4.z * FPAD + d]);
        s += __bfloat162float(t_ws[(size_t)a4.w * FPAD + d]);
      }
      sE[pl][slot] = fmaxf(s * (1.0f / (DEGREE + 1)), 0.f);
    }
    __syncthreads();

    // phase 2: h = relu(fc1 @ e + b1), one thread per (pair, i)
    if (tid < PPB * 15) {
      int pl = tid / 15;
      int i = tid - pl * 15;
      float acc = b1v[i];
#pragma unroll
      for (int j = 0; j < 30; ++j) acc += s1[i * 30 + j] * sE[pl][j];
      sHh[pl][i] = fmaxf(acc, 0.f);
    }
    __syncthreads();

    // phase 3: out = relu(fc2 @ h + b2), one thread per pair.
    // Safe without trailing barrier (next phase-2 writes to sHh are behind
    // the next chunk's first barrier; next phase-1 only touches sE).
    if (tid < PPB) {
      float acc = b2v;
#pragma unroll
      for (int i = 0; i < 15; ++i) acc += s2v[i] * sHh[tid][i];
      out[pbase + tid] = fmaxf(acc, 0.f);
    }
    __syncthreads();
  }
}

// ---------------------------------------------------------------------------
extern "C" void kernel_launch(void* const* d_in, const int* in_sizes, int n_in,
                              void* d_out, int out_size, void* d_ws,
                              size_t ws_size, hipStream_t stream) {
  const int* to_pred = (const int*)d_in[0];
  const int* adj     = (const int*)d_in[1];
  const float* feat  = (const float*)d_in[2];
  const float* W1    = (const float*)d_in[3];
  const float* W2    = (const float*)d_in[4];
  const float* fc1_w = (const float*)d_in[5];
  const float* fc1_b = (const float*)d_in[6];
  const float* fc2_w = (const float*)d_in[7];
  const float* fc2_b = (const float*)d_in[8];
  float* out         = (float*)d_out;

  __hip_bfloat16* t_ws = (__hip_bfloat16*)d_ws;  // 100000*16*2 = 3.2 MB

  int grid1 = (N_NODES + NPB * NCH1 - 1) / (NPB * NCH1);  // 893
  k_node_all<<<grid1, 256, 0, stream>>>(adj, feat, W1, W2, t_ws);

  int grid2 = N_PAIRS / (PPB * NCH2);                     // 256
  k_pair_all<<<grid2, 256, 0, stream>>>(to_pred, adj, t_ws, fc1_w, fc1_b,
                                        fc2_w, fc2_b, out);
}

// Round 5
// 115.309 us; speedup vs baseline: 1.2040x; 1.2040x over previous
//
#include <hip/hip_runtime.h>
#include <hip/hip_bf16.h>

#define N_NODES 100000
#define DEGREE 32
#define N_PAIRS 8192
#define FEAT 9
#define HID 20
#define NOUT 15
#define FPAD 16   // padded row stride (elements) for the bf16 t table (32B rows)

#define NPB 28    // nodes per block in K1 (28*9 = 252 active lanes of 256)
#define PPB 8     // pairs per block in K2 (8*30 = 240 active lanes of 256)

// ---------------------------------------------------------------------------
// K1: fused enc1-mean + node MLP. r0 structure (grid 3572, no chunking —
//   latency-bound gathers want max independent blocks), with the gather
//   phase restructured for ILP: all 8 adj int4 loads and all 32 feat gathers
//   are issued into registers BEFORE any reduction. r4's VGPR=28 showed the
//   accumulate-chain form starved memory-level parallelism (52 us, 7% HBM,
//   all pipes idle). __launch_bounds__(256,4): <=128 VGPR, >=16 waves/CU.
// ---------------------------------------------------------------------------
__global__ __launch_bounds__(256, 4) void k_node_all(
    const int* __restrict__ adj,
    const float* __restrict__ feat,
    const float* __restrict__ W1,   // [HID][2*FEAT]
    const float* __restrict__ W2,   // [NOUT][HID]
    __hip_bfloat16* __restrict__ t_ws) {
  __shared__ float sW1[HID * 2 * FEAT];   // 360
  __shared__ float sW2[NOUT * HID];       // 300
  __shared__ float sComb[NPB][2 * FEAT];  // 28 x 18
  __shared__ float sH[NPB][HID];          // 28 x 20

  int tid = threadIdx.x;
  for (int i = tid; i < HID * 2 * FEAT; i += 256) sW1[i] = W1[i];
  for (int i = tid; i < NOUT * HID; i += 256) sW2[i] = W2[i];
  // first barrier below also covers the weight staging

  int base = blockIdx.x * NPB;

  // phase 1: [self feat | neighbor mean] -> sComb, ILP-forced gathers
  if (tid < NPB * FEAT) {
    int nl = tid / FEAT;
    int j = tid - nl * FEAT;
    int n = base + nl;
    if (n < N_NODES) {
      const int4* arow4 = (const int4*)(adj + (size_t)n * DEGREE);
      int4 a[DEGREE / 4];
#pragma unroll
      for (int c = 0; c < DEGREE / 4; ++c) a[c] = arow4[c];  // 8 independent

      float selfv = feat[(size_t)n * FEAT + j];

      float v[DEGREE];
#pragma unroll
      for (int c = 0; c < DEGREE / 4; ++c) {   // 32 independent gathers
        v[4 * c + 0] = feat[(size_t)a[c].x * FEAT + j];
        v[4 * c + 1] = feat[(size_t)a[c].y * FEAT + j];
        v[4 * c + 2] = feat[(size_t)a[c].z * FEAT + j];
        v[4 * c + 3] = feat[(size_t)a[c].w * FEAT + j];
      }
      // pairwise tree reduction (short dep chain, static indices)
#pragma unroll
      for (int st = 1; st < DEGREE; st <<= 1)
#pragma unroll
        for (int i = 0; i < DEGREE; i += 2 * st) v[i] += v[i + st];

      sComb[nl][j] = selfv;
      sComb[nl][FEAT + j] = v[0] * (1.0f / DEGREE);
    }
  }
  __syncthreads();

  // phase 2: h1 = relu(W1 @ comb), one thread per (node, hid)
  for (int idx = tid; idx < NPB * HID; idx += 256) {
    int nl = idx / HID;
    int i = idx - nl * HID;
    if (base + nl < N_NODES) {
      float acc = 0.f;
#pragma unroll
      for (int j = 0; j < 2 * FEAT; ++j)
        acc += sW1[i * 2 * FEAT + j] * sComb[nl][j];
      sH[nl][i] = fmaxf(acc, 0.f);
    }
  }
  __syncthreads();

  // phase 3: t = W2 @ h1 (linear; relu comes after the enc2 mean).
  // bf16 stride-16 rows so K2's 15-lane 30B gather = one aligned 32B segment.
  for (int idx = tid; idx < NPB * NOUT; idx += 256) {
    int nl = idx / NOUT;
    int d = idx - nl * NOUT;
    int n = base + nl;
    if (n < N_NODES) {
      float acc = 0.f;
#pragma unroll
      for (int i = 0; i < HID; ++i) acc += sW2[d * HID + i] * sH[nl][i];
      t_ws[(size_t)n * FPAD + d] = __float2bfloat16(acc);
    }
  }
}

// ---------------------------------------------------------------------------
// K2: fused enc2 endpoint aggregation + pair MLP. Same ILP-forced gather
//   pattern: 8 adj int4 + 33 t-gathers (each one aligned 32B segment, bf16
//   stride-16 rows) issued before the reduction.
// ---------------------------------------------------------------------------
__global__ __launch_bounds__(256, 4) void k_pair_all(
    const int* __restrict__ to_pred,
    const int* __restrict__ adj,
    const __hip_bfloat16* __restrict__ t_ws,
    const float* __restrict__ fc1_w,  // [15][30]
    const float* __restrict__ fc1_b,  // [15]
    const float* __restrict__ fc2_w,  // [1][15]
    const float* __restrict__ fc2_b,  // [1]
    float* __restrict__ out) {
  __shared__ float s1[15 * 30];
  __shared__ float b1v[15];
  __shared__ float s2v[15];
  __shared__ float b2v;
  __shared__ float sE[PPB][30];
  __shared__ float sHh[PPB][15];

  int tid = threadIdx.x;
  for (int i = tid; i < 15 * 30; i += 256) s1[i] = fc1_w[i];
  if (tid < 15) {
    b1v[tid] = fc1_b[tid];
    s2v[tid] = fc2_w[tid];
  }
  if (tid == 0) b2v = fc2_b[0];

  int pbase = blockIdx.x * PPB;

  // phase 1: endpoint aggregate (self + 32 neighbors of t, relu(mean))
  if (tid < PPB * 30) {
    int pl = tid / 30;
    int slot = tid - pl * 30;
    int side = slot / 15;
    int d = slot - side * 15;
    int p = pbase + pl;                 // N_PAIRS % PPB == 0: always in range
    int node = to_pred[2 * p + side];
    const int4* arow4 = (const int4*)(adj + (size_t)node * DEGREE);
    int4 a[DEGREE / 4];
#pragma unroll
    for (int c = 0; c < DEGREE / 4; ++c) a[c] = arow4[c];

    float v[DEGREE + 1];
    v[DEGREE] = __bfloat162float(t_ws[(size_t)node * FPAD + d]);  // self term
#pragma unroll
    for (int c = 0; c < DEGREE / 4; ++c) {   // 32 independent gathers
      v[4 * c + 0] = __bfloat162float(t_ws[(size_t)a[c].x * FPAD + d]);
      v[4 * c + 1] = __bfloat162float(t_ws[(size_t)a[c].y * FPAD + d]);
      v[4 * c + 2] = __bfloat162float(t_ws[(size_t)a[c].z * FPAD + d]);
      v[4 * c + 3] = __bfloat162float(t_ws[(size_t)a[c].w * FPAD + d]);
    }
#pragma unroll
    for (int st = 1; st < DEGREE; st <<= 1)
#pragma unroll
      for (int i = 0; i < DEGREE; i += 2 * st) v[i] += v[i + st];

    sE[pl][slot] = fmaxf((v[0] + v[DEGREE]) * (1.0f / (DEGREE + 1)), 0.f);
  }
  __syncthreads();

  // phase 2: h = relu(fc1 @ e + b1), one thread per (pair, i)
  if (tid < PPB * 15) {
    int pl = tid / 15;
    int i = tid - pl * 15;
    float acc = b1v[i];
#pragma unroll
    for (int j = 0; j < 30; ++j) acc += s1[i * 30 + j] * sE[pl][j];
    sHh[pl][i] = fmaxf(acc, 0.f);
  }
  __syncthreads();

  // phase 3: out = relu(fc2 @ h + b2), one thread per pair
  if (tid < PPB) {
    float acc = b2v;
#pragma unroll
    for (int i = 0; i < 15; ++i) acc += s2v[i] * sHh[tid][i];
    out[pbase + tid] = fmaxf(acc, 0.f);
  }
}

// ---------------------------------------------------------------------------
extern "C" void kernel_launch(void* const* d_in, const int* in_sizes, int n_in,
                              void* d_out, int out_size, void* d_ws,
                              size_t ws_size, hipStream_t stream) {
  const int* to_pred = (const int*)d_in[0];
  const int* adj     = (const int*)d_in[1];
  const float* feat  = (const float*)d_in[2];
  const float* W1    = (const float*)d_in[3];
  const float* W2    = (const float*)d_in[4];
  const float* fc1_w = (const float*)d_in[5];
  const float* fc1_b = (const float*)d_in[6];
  const float* fc2_w = (const float*)d_in[7];
  const float* fc2_b = (const float*)d_in[8];
  float* out         = (float*)d_out;

  __hip_bfloat16* t_ws = (__hip_bfloat16*)d_ws;  // 100000*16*2 = 3.2 MB

  int grid1 = (N_NODES + NPB - 1) / NPB;   // 3572
  k_node_all<<<grid1, 256, 0, stream>>>(adj, feat, W1, W2, t_ws);

  int grid2 = N_PAIRS / PPB;               // 1024
  k_pair_all<<<grid2, 256, 0, stream>>>(to_pred, adj, t_ws, fc1_w, fc1_b,
                                        fc2_w, fc2_b, out);
}